// Round 1
// baseline (4309.764 us; speedup 1.0000x reference)
//
#include <hip/hip_runtime.h>
#include <hip/hip_bf16.h>

#define DIMc 1024
#define Hc   16
#define DHc  64
#define Bc   4
#define Tc   1024

// ---------------------------------------------------------------------------
// GEMM (B-transposed weights):  C[m][n] = sum_k A[m][k] * W[n][k] (+ bias[n])
// SPLIT=1: write C to [b, h, t, dh] head-split layout (m = b*T+t, n = h*64+dh)
// SPLIT=0: write C to plain [m][n]
// Tile: 64x64, BK=16, 256 threads, 4x4 microtile per thread.
// ---------------------------------------------------------------------------
template <int SPLIT>
__global__ __launch_bounds__(256) void gemm_bt(const float* __restrict__ A,
                                               const float* __restrict__ W,
                                               const float* __restrict__ bias,
                                               float* __restrict__ out) {
  __shared__ float As[16][65];  // As[k][m], +1 pad
  __shared__ float Ws[16][65];  // Ws[k][n]
  const int tid = threadIdx.x;
  const int bm = blockIdx.x * 64;
  const int bn = blockIdx.y * 64;
  const int lr = tid >> 2;         // 0..63  (row within tile for loads)
  const int lc = (tid & 3) << 2;   // 0,4,8,12 (k offset for loads)
  const int ty = tid >> 4;         // 0..15
  const int tx = tid & 15;         // 0..15

  float acc[4][4] = {};
  const float* Arow = A + (size_t)(bm + lr) * DIMc + lc;
  const float* Wrow = W + (size_t)(bn + lr) * DIMc + lc;

  for (int k0 = 0; k0 < DIMc; k0 += 16) {
    const float4 a4 = *reinterpret_cast<const float4*>(Arow + k0);
    const float4 w4 = *reinterpret_cast<const float4*>(Wrow + k0);
    __syncthreads();
    As[lc + 0][lr] = a4.x; As[lc + 1][lr] = a4.y;
    As[lc + 2][lr] = a4.z; As[lc + 3][lr] = a4.w;
    Ws[lc + 0][lr] = w4.x; Ws[lc + 1][lr] = w4.y;
    Ws[lc + 2][lr] = w4.z; Ws[lc + 3][lr] = w4.w;
    __syncthreads();
#pragma unroll
    for (int k = 0; k < 16; ++k) {
      const float a0 = As[k][ty * 4 + 0];
      const float a1 = As[k][ty * 4 + 1];
      const float a2 = As[k][ty * 4 + 2];
      const float a3 = As[k][ty * 4 + 3];
      const float w0 = Ws[k][tx * 4 + 0];
      const float w1 = Ws[k][tx * 4 + 1];
      const float w2 = Ws[k][tx * 4 + 2];
      const float w3 = Ws[k][tx * 4 + 3];
      acc[0][0] += a0 * w0; acc[0][1] += a0 * w1; acc[0][2] += a0 * w2; acc[0][3] += a0 * w3;
      acc[1][0] += a1 * w0; acc[1][1] += a1 * w1; acc[1][2] += a1 * w2; acc[1][3] += a1 * w3;
      acc[2][0] += a2 * w0; acc[2][1] += a2 * w1; acc[2][2] += a2 * w2; acc[2][3] += a2 * w3;
      acc[3][0] += a3 * w0; acc[3][1] += a3 * w1; acc[3][2] += a3 * w2; acc[3][3] += a3 * w3;
    }
  }

#pragma unroll
  for (int i = 0; i < 4; ++i) {
    const int m = bm + ty * 4 + i;
#pragma unroll
    for (int j = 0; j < 4; ++j) {
      const int n = bn + tx * 4 + j;
      const float v = acc[i][j] + (bias ? bias[n] : 0.f);
      if (SPLIT) {
        const int b = m >> 10, t = m & (Tc - 1);
        const int h = n >> 6, dh = n & (DHc - 1);
        out[(((size_t)b * Hc + h) * Tc + t) * DHc + dh] = v;
      } else {
        out[(size_t)m * DIMc + n] = v;
      }
    }
  }
}

// ---------------------------------------------------------------------------
// Attention: one workgroup per (b, h, 8 q-rows). 256 threads.
// scores[r][k] = ( (q[r]+u)·K[k] + shifted_pos ) / 8 ; softmax ; PV.
// Relative shift (derived from the reference reshape trick, T=Tq=Tk):
//   k <= q   : pos_s[q,   k-q+T-1]
//   k == q+1 : 0
//   k >  q+1 : pos_s[q+1, k-q-2]
// Scatter form: source row qs contributes pos_s[qs][j] to
//   (row qs,   k = j+qs-(T-1))  when j >= T-1-qs      [diag, k <= qs]
//   (row qs-1, k = j+qs+1)      when j+qs+1 <= T-1    [wrap, k >= qs+1]
// These regions are disjoint per row -> race-free LDS +=.
// ---------------------------------------------------------------------------
__global__ __launch_bounds__(256) void attn_kernel(
    const float* __restrict__ Q, const float* __restrict__ K,
    const float* __restrict__ V, const float* __restrict__ P,
    const float* __restrict__ bu, const float* __restrict__ bv,
    float* __restrict__ ctx) {
  constexpr int QB = 8;
  __shared__ float sc[QB][Tc];      // 32 KB scores
  __shared__ float qu[QB][DHc];
  __shared__ float qv[QB + 1][DHc];
  __shared__ float sm[QB];

  const int tid = threadIdx.x;
  const int wg = blockIdx.x;
  const int qb = wg & (Tc / QB - 1);
  const int h = (wg >> 7) & (Hc - 1);
  const int b = wg >> 11;
  const int q0 = qb * QB;
  const float scale = 0.125f;  // 1/sqrt(64), folded into qu/qv

  // stage qu (QB rows) and qv (QB+1 rows, incl. next-block row for the wrap)
  for (int i = tid; i < (QB + 1) * DHc; i += 256) {
    const int r = i >> 6, d = i & 63;
    const int q = q0 + r;
    const float qval =
        (q < Tc) ? Q[(((size_t)b * Hc + h) * Tc + q) * DHc + d] : 0.f;
    if (r < QB) qu[r][d] = (qval + bu[h * DHc + d]) * scale;
    qv[r][d] = (qval + bv[h * DHc + d]) * scale;
  }
  __syncthreads();

  // ---- content scores ----
  const float* Kb = K + ((size_t)b * Hc + h) * Tc * DHc;
  for (int k = tid; k < Tc; k += 256) {
    const float* kr = Kb + (size_t)k * DHc;
    float acc[QB] = {};
#pragma unroll
    for (int d4 = 0; d4 < DHc; d4 += 4) {
      const float4 kv = *reinterpret_cast<const float4*>(kr + d4);
#pragma unroll
      for (int r = 0; r < QB; ++r) {
        const float4 q4 = *reinterpret_cast<const float4*>(&qu[r][d4]);
        acc[r] += q4.x * kv.x + q4.y * kv.y + q4.z * kv.z + q4.w * kv.w;
      }
    }
#pragma unroll
    for (int r = 0; r < QB; ++r) sc[r][k] = acc[r];
  }
  __syncthreads();

  // ---- position scores + relative-shift scatter ----
  const float* Pb = P + (size_t)h * Tc * DHc;
  for (int j = tid; j < Tc; j += 256) {
    const float* pr = Pb + (size_t)j * DHc;
    float ps[QB + 1] = {};
#pragma unroll
    for (int d4 = 0; d4 < DHc; d4 += 4) {
      const float4 pv = *reinterpret_cast<const float4*>(pr + d4);
#pragma unroll
      for (int r = 0; r <= QB; ++r) {
        const float4 q4 = *reinterpret_cast<const float4*>(&qv[r][d4]);
        ps[r] += q4.x * pv.x + q4.y * pv.y + q4.z * pv.z + q4.w * pv.w;
      }
    }
#pragma unroll
    for (int r = 0; r <= QB; ++r) {
      const int qs = q0 + r;
      if (r < QB && j >= (Tc - 1) - qs) sc[r][j + qs - (Tc - 1)] += ps[r];
      if (r >= 1 && j + qs + 1 < Tc) sc[r - 1][j + qs + 1] += ps[r];
    }
  }
  __syncthreads();

  // ---- softmax: 32 lanes per row ----
  {
    const int r = tid >> 5;
    const int ln = tid & 31;
    float mx = -1e30f;
    for (int k = ln; k < Tc; k += 32) mx = fmaxf(mx, sc[r][k]);
#pragma unroll
    for (int m = 16; m >= 1; m >>= 1) mx = fmaxf(mx, __shfl_xor(mx, m, 64));
    float s = 0.f;
    for (int k = ln; k < Tc; k += 32) {
      const float e = __expf(sc[r][k] - mx);
      sc[r][k] = e;
      s += e;
    }
#pragma unroll
    for (int m = 16; m >= 1; m >>= 1) s += __shfl_xor(s, m, 64);
    if (ln == 0) sm[r] = s;
  }
  __syncthreads();

  // ---- PV: 64 d-lanes x 4 k-stripes ----
  const float* Vb = V + ((size_t)b * Hc + h) * Tc * DHc;
  const int d = tid & 63, sb = tid >> 6;
  float av[QB] = {};
  for (int k = sb; k < Tc; k += 4) {
    const float vv = Vb[(size_t)k * DHc + d];
#pragma unroll
    for (int r = 0; r < QB; ++r) av[r] += sc[r][k] * vv;
  }
  __syncthreads();  // everyone done reading sc before we reuse it as scratch
  float* part = &sc[0][0];
#pragma unroll
  for (int r = 0; r < QB; ++r) part[(sb * QB + r) * 64 + d] = av[r];
  __syncthreads();
  for (int i = tid; i < QB * DHc; i += 256) {
    const int r = i >> 6, d2 = i & 63;
    float s = part[(0 * QB + r) * 64 + d2] + part[(1 * QB + r) * 64 + d2] +
              part[(2 * QB + r) * 64 + d2] + part[(3 * QB + r) * 64 + d2];
    s /= sm[r];
    ctx[((size_t)b * Tc + (q0 + r)) * DIMc + h * DHc + d2] = s;
  }
}

// ---------------------------------------------------------------------------
extern "C" void kernel_launch(void* const* d_in, const int* in_sizes, int n_in,
                              void* d_out, int out_size, void* d_ws,
                              size_t ws_size, hipStream_t stream) {
  const float* x   = (const float*)d_in[0];
  const float* pos = (const float*)d_in[1];
  // d_in[2] = mask: all-True in this problem, no-op in the reference -> unused
  const float* Wq  = (const float*)d_in[3];
  const float* bq  = (const float*)d_in[4];
  const float* Wk  = (const float*)d_in[5];
  const float* bk  = (const float*)d_in[6];
  const float* Wv  = (const float*)d_in[7];
  const float* bv  = (const float*)d_in[8];
  const float* Wp  = (const float*)d_in[9];
  const float* Wo  = (const float*)d_in[10];
  const float* bo  = (const float*)d_in[11];
  const float* pbu = (const float*)d_in[12];
  const float* pbv = (const float*)d_in[13];
  float* out = (float*)d_out;

  float* ws = (float*)d_ws;
  float* Qw = ws;                  // [B,H,T,64]  16 MB
  float* Kw = ws + 4194304;        // [B,H,T,64]  16 MB
  float* Vw = ws + 8388608;        // [B,H,T,64]  16 MB
  float* Pw = ws + 12582912;       // [H,T,64]     4 MB
  float* Cw = ws + 13631488;       // [B,T,DIM]   16 MB

  const dim3 blk(256);
  const dim3 gProj(64, 16);   // M=4096, N=1024
  const dim3 gPos(16, 16);    // M=1024, N=1024
  const dim3 gAttn(Bc * Hc * (Tc / 8));

  hipLaunchKernelGGL((gemm_bt<1>), gProj, blk, 0, stream, x, Wq, bq, Qw);
  hipLaunchKernelGGL((gemm_bt<1>), gProj, blk, 0, stream, x, Wk, bk, Kw);
  hipLaunchKernelGGL((gemm_bt<1>), gProj, blk, 0, stream, x, Wv, bv, Vw);
  hipLaunchKernelGGL((gemm_bt<1>), gPos, blk, 0, stream, pos, Wp, nullptr, Pw);
  hipLaunchKernelGGL(attn_kernel, gAttn, blk, 0, stream, Qw, Kw, Vw, Pw, pbu,
                     pbv, Cw);
  hipLaunchKernelGGL((gemm_bt<0>), gProj, blk, 0, stream, Cw, Wo, bo, out);
}

// Round 2
// 543.544 us; speedup vs baseline: 7.9290x; 7.9290x over previous
//
#include <hip/hip_runtime.h>
#include <hip/hip_bf16.h>

#define DIMc 1024
#define Hc   16
#define DHc  64
#define Bc   4
#define Tc   1024

typedef __attribute__((ext_vector_type(8))) short s16x8;
typedef __attribute__((ext_vector_type(4))) float f32x4;

__device__ inline short f2bf(float x) {
  unsigned u = __float_as_uint(x);
  u += 0x7fffu + ((u >> 16) & 1u);   // RNE
  return (short)(u >> 16);
}
__device__ inline float bf2f(short s) {
  return __uint_as_float(((unsigned)(unsigned short)s) << 16);
}

#define MFMA16(a, b, c) __builtin_amdgcn_mfma_f32_16x16x32_bf16((a), (b), (c), 0, 0, 0)

// ---------------------------------------------------------------------------
// f32 -> bf16 cast, 8 elems/thread
// ---------------------------------------------------------------------------
__global__ __launch_bounds__(256) void cast_f32_bf16(const float* __restrict__ in,
                                                     short* __restrict__ out, int n) {
  const int i = (blockIdx.x * 256 + threadIdx.x) * 8;
  if (i >= n) return;
  const float4 a = *(const float4*)(in + i);
  const float4 b = *(const float4*)(in + i + 4);
  s16x8 r;
  r[0] = f2bf(a.x); r[1] = f2bf(a.y); r[2] = f2bf(a.z); r[3] = f2bf(a.w);
  r[4] = f2bf(b.x); r[5] = f2bf(b.y); r[6] = f2bf(b.z); r[7] = f2bf(b.w);
  *(s16x8*)(out + i) = r;
}

// ---------------------------------------------------------------------------
// MFMA GEMM:  C[m][n] = sum_k A[m][k]*B[n][k]  (both K-major "B^T" form)
// 128x128 tile, BK=32, 256 thr = 4 waves (2x2), 4x4 16x16 frags per wave.
// Reg-staged LDS, padded stride 36 (72 B) -> ~2-way conflicts max.
// EPI 0: f32 out [m][N] + bias          (final Wo GEMM -> d_out)
// EPI 1: bf16 out head-split [b,h,t,dh] (+ optional bias)       (K,V,P proj)
// EPI 2: dual bf16 head-split: (v+bu)*0.125 and (v+bv)*0.125    (Q proj)
// EPI 3: bf16 out [z][m][N] batched     (pos_s)
// ---------------------------------------------------------------------------
template <int EPI>
__global__ __launch_bounds__(256) void mfma_gemm(
    const short* __restrict__ A, const short* __restrict__ B,
    const float* __restrict__ bias,
    float* __restrict__ Cf, short* __restrict__ Cb1, short* __restrict__ Cb2,
    const float* __restrict__ bu, const float* __restrict__ bv,
    int N, int K, int ldA, int ldB,
    long zA, long zB, long zC, int bmod) {
  __shared__ short As[128 * 36];
  __shared__ short Bs[128 * 36];

  const int z = blockIdx.z;
  const short* Ab = A + (long)z * zA;
  const short* Bb = B + (long)(bmod ? (z & 15) : z) * zB;

  const int tid = threadIdx.x;
  const int w = tid >> 6, l = tid & 63;
  const int wr = w >> 1, wc = w & 1;
  const int ll = l & 15, lg = l >> 4;
  const int bm = blockIdx.x * 128, bn = blockIdx.y * 128;
  const int arow = tid >> 2, acol = (tid & 3) * 8;  // 64 rows x 32 k per chunk set

  const short* Ap0 = Ab + (size_t)(bm + arow) * ldA + acol;
  const short* Ap1 = Ab + (size_t)(bm + arow + 64) * ldA + acol;
  const short* Bp0 = Bb + (size_t)(bn + arow) * ldB + acol;
  const short* Bp1 = Bb + (size_t)(bn + arow + 64) * ldB + acol;

  f32x4 acc[4][4];
#pragma unroll
  for (int i = 0; i < 4; ++i)
#pragma unroll
    for (int j = 0; j < 4; ++j) acc[i][j] = (f32x4){0.f, 0.f, 0.f, 0.f};

  s16x8 a0 = *(const s16x8*)(Ap0);
  s16x8 a1 = *(const s16x8*)(Ap1);
  s16x8 b0 = *(const s16x8*)(Bp0);
  s16x8 b1 = *(const s16x8*)(Bp1);

  for (int k0 = 0; k0 < K; k0 += 32) {
    __syncthreads();
    *(s16x8*)&As[arow * 36 + acol] = a0;
    *(s16x8*)&As[(arow + 64) * 36 + acol] = a1;
    *(s16x8*)&Bs[arow * 36 + acol] = b0;
    *(s16x8*)&Bs[(arow + 64) * 36 + acol] = b1;
    const int kn = k0 + 32;
    if (kn < K) {  // prefetch next K-tile while MFMAs run
      a0 = *(const s16x8*)(Ap0 + kn);
      a1 = *(const s16x8*)(Ap1 + kn);
      b0 = *(const s16x8*)(Bp0 + kn);
      b1 = *(const s16x8*)(Bp1 + kn);
    }
    __syncthreads();
    s16x8 af[4], bf_[4];
#pragma unroll
    for (int i = 0; i < 4; ++i) {
      af[i] = *(const s16x8*)&As[(wr * 64 + i * 16 + ll) * 36 + lg * 8];
      bf_[i] = *(const s16x8*)&Bs[(wc * 64 + i * 16 + ll) * 36 + lg * 8];
    }
#pragma unroll
    for (int mi = 0; mi < 4; ++mi)
#pragma unroll
      for (int ni = 0; ni < 4; ++ni)
        acc[mi][ni] = MFMA16(af[mi], bf_[ni], acc[mi][ni]);
  }

#pragma unroll
  for (int mi = 0; mi < 4; ++mi)
#pragma unroll
    for (int ni = 0; ni < 4; ++ni)
#pragma unroll
      for (int r = 0; r < 4; ++r) {
        const int row = bm + wr * 64 + mi * 16 + lg * 4 + r;
        const int col = bn + wc * 64 + ni * 16 + ll;
        float v = acc[mi][ni][r];
        if (EPI == 0) {
          Cf[(size_t)row * N + col] = v + bias[col];
        } else if (EPI == 1) {
          if (bias) v += bias[col];
          const int b_ = row >> 10, t = row & 1023, hh = col >> 6, dh = col & 63;
          Cb1[(((size_t)b_ * Hc + hh) * Tc + t) * DHc + dh] = f2bf(v);
        } else if (EPI == 2) {
          v += bias[col];
          const int b_ = row >> 10, t = row & 1023, hh = col >> 6, dh = col & 63;
          const size_t o = (((size_t)b_ * Hc + hh) * Tc + t) * DHc + dh;
          Cb1[o] = f2bf((v + bu[col]) * 0.125f);
          Cb2[o] = f2bf((v + bv[col]) * 0.125f);
        } else {  // EPI == 3
          Cb1[(long)z * zC + (size_t)row * N + col] = f2bf(v);
        }
      }
}

// ---------------------------------------------------------------------------
// Flash attention with relative-position gather.
// Block = (qtile of 128, h, b-slice). 256 thr = 4 waves, wave owns 32 q-rows.
// Online softmax in registers; P staged to LDS for PV MFMA; V transposed into
// LDS with XOR swizzle (k ^= (d>>3)<<4) for aligned, low-conflict access.
// Shift gather (validated in round 0): k<=q -> PS[q, k-q+1023];
//   k==q+1 -> 0; k>q+1 -> PS[q+1, k-q-2].  PS is pre-scaled by 0.125.
// ---------------------------------------------------------------------------
__global__ __launch_bounds__(256) void flash_attn(
    const short* __restrict__ Qu, const short* __restrict__ Kg,
    const short* __restrict__ Vg, const short* __restrict__ PS,
    short* __restrict__ ctx, int b0) {
  __shared__ short Kt[128 * 72];   // [key][dh], pad->72
  __shared__ short Vt[64 * 136];   // [dh][key^swz], pad->136
  __shared__ short PQ[128 * 136];  // Q stage (stride 72), then P tile (stride 136)

  const int tid = threadIdx.x;
  const int w = tid >> 6, l = tid & 63;
  const int ll = l & 15, lg = l >> 4;
  const int qt = blockIdx.x, h = blockIdx.y, bl = blockIdx.z;
  const int b = b0 + bl;
  const int q0 = qt * 128;

  const size_t bh = (size_t)b * Hc + h;
  const short* Qgp = Qu + (bh * Tc + q0) * DHc;
  const short* Kgp = Kg + bh * Tc * DHc;
  const short* Vgp = Vg + bh * Tc * DHc;
  const short* PSg = PS + ((size_t)(bl * Hc + h) << 20);

  // ---- stage Q tile (stride 72) and pull A-frags into registers ----
#pragma unroll
  for (int i = 0; i < 4; ++i) {
    const int c = tid + i * 256;
    const int row = c >> 3, col8 = (c & 7) * 8;
    *(s16x8*)&PQ[row * 72 + col8] = *(const s16x8*)(Qgp + row * 64 + col8);
  }
  __syncthreads();
  s16x8 qa[2][2];
#pragma unroll
  for (int ri = 0; ri < 2; ++ri)
#pragma unroll
    for (int ks = 0; ks < 2; ++ks)
      qa[ri][ks] = *(const s16x8*)&PQ[(w * 32 + ri * 16 + ll) * 72 + ks * 32 + lg * 8];

  f32x4 o[2][4];
#pragma unroll
  for (int ri = 0; ri < 2; ++ri)
#pragma unroll
    for (int cd = 0; cd < 4; ++cd) o[ri][cd] = (f32x4){0.f, 0.f, 0.f, 0.f};
  float m_run[2][4], l_run[2][4];
#pragma unroll
  for (int ri = 0; ri < 2; ++ri)
#pragma unroll
    for (int r = 0; r < 4; ++r) { m_run[ri][r] = -3.0e38f; l_run[ri][r] = 0.f; }

  for (int kt = 0; kt < 8; ++kt) {
    // global loads (coalesced rows), consumed after barrier
    s16x8 kr[4], vr[4];
#pragma unroll
    for (int i = 0; i < 4; ++i) {
      const int c = tid + i * 256;
      const int row = c >> 3, col8 = (c & 7) * 8;
      kr[i] = *(const s16x8*)(Kgp + (size_t)(kt * 128 + row) * 64 + col8);
      vr[i] = *(const s16x8*)(Vgp + (size_t)(kt * 128 + row) * 64 + col8);
    }
    __syncthreads();  // prev iteration's LDS reads complete
#pragma unroll
    for (int i = 0; i < 4; ++i) {
      const int c = tid + i * 256;
      const int row = c >> 3, col8 = (c & 7) * 8;
      *(s16x8*)&Kt[row * 72 + col8] = kr[i];
#pragma unroll
      for (int e = 0; e < 8; ++e) {
        const int d = col8 + e;
        Vt[d * 136 + (row ^ ((d >> 3) << 4))] = vr[i][e];
      }
    }
    __syncthreads();  // staging visible

    // ---- QK^T ----
    f32x4 s[2][8];
#pragma unroll
    for (int ri = 0; ri < 2; ++ri)
#pragma unroll
      for (int ci = 0; ci < 8; ++ci) s[ri][ci] = (f32x4){0.f, 0.f, 0.f, 0.f};
#pragma unroll
    for (int ks = 0; ks < 2; ++ks) {
      s16x8 kb[8];
#pragma unroll
      for (int ci = 0; ci < 8; ++ci)
        kb[ci] = *(const s16x8*)&Kt[(ci * 16 + ll) * 72 + ks * 32 + lg * 8];
#pragma unroll
      for (int ri = 0; ri < 2; ++ri)
#pragma unroll
        for (int ci = 0; ci < 8; ++ci)
          s[ri][ci] = MFMA16(qa[ri][ks], kb[ci], s[ri][ci]);
    }

    // ---- relative-position gather ----
#pragma unroll
    for (int ri = 0; ri < 2; ++ri)
#pragma unroll
      for (int ci = 0; ci < 8; ++ci)
#pragma unroll
        for (int r = 0; r < 4; ++r) {
          const int q = q0 + w * 32 + ri * 16 + lg * 4 + r;
          const int k = kt * 128 + ci * 16 + ll;
          const int dq = k - q;
          const int qrow = (dq <= 0) ? q : q + 1;
          const int j = (dq <= 0) ? dq + 1023 : dq - 2;
          if (dq != 1) s[ri][ci][r] += bf2f(PSg[(size_t)qrow * 1024 + j]);
        }

    // ---- online softmax (rows live in 16-lane groups) ----
    float fac[2][4];
#pragma unroll
    for (int ri = 0; ri < 2; ++ri)
#pragma unroll
      for (int r = 0; r < 4; ++r) {
        float mx = s[ri][0][r];
#pragma unroll
        for (int ci = 1; ci < 8; ++ci) mx = fmaxf(mx, s[ri][ci][r]);
        mx = fmaxf(mx, __shfl_xor(mx, 1));
        mx = fmaxf(mx, __shfl_xor(mx, 2));
        mx = fmaxf(mx, __shfl_xor(mx, 4));
        mx = fmaxf(mx, __shfl_xor(mx, 8));
        const float mnew = fmaxf(m_run[ri][r], mx);
        const float f = __expf(m_run[ri][r] - mnew);
        float lsum = 0.f;
#pragma unroll
        for (int ci = 0; ci < 8; ++ci) {
          const float e = __expf(s[ri][ci][r] - mnew);
          s[ri][ci][r] = e;
          lsum += e;
        }
        lsum += __shfl_xor(lsum, 1);
        lsum += __shfl_xor(lsum, 2);
        lsum += __shfl_xor(lsum, 4);
        lsum += __shfl_xor(lsum, 8);
        m_run[ri][r] = mnew;
        l_run[ri][r] = l_run[ri][r] * f + lsum;
        fac[ri][r] = f;
      }
#pragma unroll
    for (int ri = 0; ri < 2; ++ri)
#pragma unroll
      for (int cd = 0; cd < 4; ++cd)
#pragma unroll
        for (int r = 0; r < 4; ++r) o[ri][cd][r] *= fac[ri][r];

    // ---- P -> LDS (bf16, stride 136) ----
#pragma unroll
    for (int ri = 0; ri < 2; ++ri)
#pragma unroll
      for (int ci = 0; ci < 8; ++ci)
#pragma unroll
        for (int r = 0; r < 4; ++r)
          PQ[(w * 32 + ri * 16 + lg * 4 + r) * 136 + ci * 16 + ll] = f2bf(s[ri][ci][r]);
    __syncthreads();  // P + V visible to all

    // ---- PV ----
#pragma unroll
    for (int ks = 0; ks < 4; ++ks) {
      s16x8 pa[2], vv[4];
#pragma unroll
      for (int ri = 0; ri < 2; ++ri)
        pa[ri] = *(const s16x8*)&PQ[(w * 32 + ri * 16 + ll) * 136 + ks * 32 + lg * 8];
#pragma unroll
      for (int cd = 0; cd < 4; ++cd) {
        const int d = cd * 16 + ll;
        vv[cd] = *(const s16x8*)&Vt[d * 136 + ((ks * 32 + lg * 8) ^ ((d >> 3) << 4))];
      }
#pragma unroll
      for (int ri = 0; ri < 2; ++ri)
#pragma unroll
        for (int cd = 0; cd < 4; ++cd)
          o[ri][cd] = MFMA16(pa[ri], vv[cd], o[ri][cd]);
    }
  }

  // ---- finalize: /l, write ctx [b, t, h*64+d] bf16 ----
#pragma unroll
  for (int ri = 0; ri < 2; ++ri)
#pragma unroll
    for (int r = 0; r < 4; ++r) {
      const float inv = 1.f / l_run[ri][r];
      const int row = q0 + w * 32 + ri * 16 + lg * 4 + r;
#pragma unroll
      for (int cd = 0; cd < 4; ++cd) {
        const int d = cd * 16 + ll;
        ctx[((size_t)b * Tc + row) * DIMc + h * DHc + d] = f2bf(o[ri][cd][r] * inv);
      }
    }
}

// ---------------------------------------------------------------------------
extern "C" void kernel_launch(void* const* d_in, const int* in_sizes, int n_in,
                              void* d_out, int out_size, void* d_ws,
                              size_t ws_size, hipStream_t stream) {
  const float* x   = (const float*)d_in[0];
  const float* pos = (const float*)d_in[1];
  // d_in[2] = mask (all-True, unused)
  const float* Wq  = (const float*)d_in[3];
  const float* bq  = (const float*)d_in[4];
  const float* Wk  = (const float*)d_in[5];
  const float* bk  = (const float*)d_in[6];
  const float* Wv  = (const float*)d_in[7];
  const float* bv  = (const float*)d_in[8];
  const float* Wp  = (const float*)d_in[9];
  const float* Wo  = (const float*)d_in[10];
  const float* bo  = (const float*)d_in[11];
  const float* pbu = (const float*)d_in[12];
  const float* pbv = (const float*)d_in[13];
  float* out = (float*)d_out;

  char* ws = (char*)d_ws;
  const size_t MB = 1024 * 1024;
  short* xb  = (short*)(ws + 0 * MB);    // x bf16        8 MB
  short* pb  = (short*)(ws + 8 * MB);    // pos bf16      2 MB
  short* Wqb = (short*)(ws + 10 * MB);
  short* Wkb = (short*)(ws + 12 * MB);
  short* Wvb = (short*)(ws + 14 * MB);
  short* Wpb = (short*)(ws + 16 * MB);
  short* Wob = (short*)(ws + 18 * MB);
  short* Quw = (short*)(ws + 20 * MB);   // (q+bq+bu)/8  [b,h,t,64] 8 MB
  short* Qvw = (short*)(ws + 28 * MB);   // (q+bq+bv)/8  [b,h,t,64] 8 MB
  short* Kw  = (short*)(ws + 36 * MB);   // [b,h,t,64]    8 MB
  short* Vw  = (short*)(ws + 44 * MB);   // [b,h,t,64]    8 MB
  short* Pw  = (short*)(ws + 52 * MB);   // [h,t,64]      2 MB
  short* PSw = (short*)(ws + 54 * MB);   // pos_s slice [2b*16h,1024,1024] 64 MB
  short* Cw  = (short*)(ws + 118 * MB);  // ctx bf16 [b,t,1024]  8 MB

  const dim3 blk(256);
  auto cast = [&](const float* in, short* o_, int n) {
    hipLaunchKernelGGL(cast_f32_bf16, dim3(n / 2048), blk, 0, stream, in, o_, n);
  };
  cast(x, xb, 4194304);
  cast(pos, pb, 1048576);
  cast(Wq, Wqb, 1048576);
  cast(Wk, Wkb, 1048576);
  cast(Wv, Wvb, 1048576);
  cast(Wp, Wpb, 1048576);
  cast(Wo, Wob, 1048576);

  // projections
  hipLaunchKernelGGL((mfma_gemm<2>), dim3(32, 8, 1), blk, 0, stream,
                     xb, Wqb, bq, nullptr, Quw, Qvw, pbu, pbv,
                     1024, 1024, 1024, 1024, 0L, 0L, 0L, 0);
  hipLaunchKernelGGL((mfma_gemm<1>), dim3(32, 8, 1), blk, 0, stream,
                     xb, Wkb, bk, nullptr, Kw, nullptr, nullptr, nullptr,
                     1024, 1024, 1024, 1024, 0L, 0L, 0L, 0);
  hipLaunchKernelGGL((mfma_gemm<1>), dim3(32, 8, 1), blk, 0, stream,
                     xb, Wvb, bv, nullptr, Vw, nullptr, nullptr, nullptr,
                     1024, 1024, 1024, 1024, 0L, 0L, 0L, 0);
  hipLaunchKernelGGL((mfma_gemm<1>), dim3(8, 8, 1), blk, 0, stream,
                     pb, Wpb, nullptr, nullptr, Pw, nullptr, nullptr, nullptr,
                     1024, 1024, 1024, 1024, 0L, 0L, 0L, 0);

  // pos_s + flash, sliced over 2 batches to bound workspace (64 MB slice)
  for (int b0 = 0; b0 < 4; b0 += 2) {
    hipLaunchKernelGGL((mfma_gemm<3>), dim3(8, 8, 32), blk, 0, stream,
                       Qvw + (size_t)b0 * 16 * 65536, Pw, nullptr, nullptr, PSw,
                       nullptr, nullptr, nullptr,
                       1024, 64, 64, 64, 65536L, 65536L, 1L << 20, 1);
    hipLaunchKernelGGL(flash_attn, dim3(8, 16, 2), blk, 0, stream,
                       Quw, Kw, Vw, PSw, Cw, b0);
  }

  // output projection (f32 out)
  hipLaunchKernelGGL((mfma_gemm<0>), dim3(32, 8, 1), blk, 0, stream,
                     Cw, Wob, bo, out, nullptr, nullptr, nullptr, nullptr,
                     1024, 1024, 1024, 1024, 0L, 0L, 0L, 0);
}

// Round 3
// 271.140 us; speedup vs baseline: 15.8950x; 2.0047x over previous
//
#include <hip/hip_runtime.h>
#include <hip/hip_bf16.h>

#define DIMc 1024
#define Hc   16
#define DHc  64
#define Bc   4
#define Tc   1024

typedef __attribute__((ext_vector_type(8))) short s16x8;
typedef __attribute__((ext_vector_type(4))) float f32x4;

__device__ inline short f2bf(float x) {
  unsigned u = __float_as_uint(x);
  u += 0x7fffu + ((u >> 16) & 1u);   // RNE
  return (short)(u >> 16);
}
__device__ inline float bf2f(short s) {
  return __uint_as_float(((unsigned)(unsigned short)s) << 16);
}

#define MFMA16(a, b, c) __builtin_amdgcn_mfma_f32_16x16x32_bf16((a), (b), (c), 0, 0, 0)

// ---------------------------------------------------------------------------
// f32 -> bf16 cast, 8 elems/thread
// ---------------------------------------------------------------------------
__global__ __launch_bounds__(256) void cast_f32_bf16(const float* __restrict__ in,
                                                     short* __restrict__ out, int n) {
  const int i = (blockIdx.x * 256 + threadIdx.x) * 8;
  if (i >= n) return;
  const float4 a = *(const float4*)(in + i);
  const float4 b = *(const float4*)(in + i + 4);
  s16x8 r;
  r[0] = f2bf(a.x); r[1] = f2bf(a.y); r[2] = f2bf(a.z); r[3] = f2bf(a.w);
  r[4] = f2bf(b.x); r[5] = f2bf(b.y); r[6] = f2bf(b.z); r[7] = f2bf(b.w);
  *(s16x8*)(out + i) = r;
}

// ---------------------------------------------------------------------------
// MFMA GEMM:  C[m][n] = sum_k A[m][k]*B[n][k]  (both K-major "B^T" form)
// 128x128 tile, BK=32, 256 thr = 4 waves (2x2), 4x4 16x16 frags per wave.
// EPI 0: f32 out [m][N] + bias          (final Wo GEMM -> d_out)
// EPI 1: bf16 out head-split [b,h,t,dh] (+ optional bias)       (K,V,P proj)
// EPI 2: dual bf16 head-split: (v+bu)*0.125 and (v+bv)*0.125    (Q proj)
// EPI 4: bf16 SHIFTED pos-score write: source (row=qs, col=j) scatters to
//        diag  (qs,   j+qs-1023)  when j >= 1023-qs
//        wrap  (qs-1, j+qs+1)     when qs>=1 && j+qs+1 <= 1023
//        zero  (qs,   qs+1)       when j==1023 && qs<1023
//        (full coverage of [q][k], exactly one writer per cell -> race-free)
// ---------------------------------------------------------------------------
template <int EPI>
__global__ __launch_bounds__(256) void mfma_gemm(
    const short* __restrict__ A, const short* __restrict__ B,
    const float* __restrict__ bias,
    float* __restrict__ Cf, short* __restrict__ Cb1, short* __restrict__ Cb2,
    const float* __restrict__ bu, const float* __restrict__ bv,
    int N, int K, int ldA, int ldB,
    long zA, long zB, long zC, int bmod) {
  __shared__ short As[128 * 36];
  __shared__ short Bs[128 * 36];

  const int z = blockIdx.z;
  const short* Ab = A + (long)z * zA;
  const short* Bb = B + (long)(bmod ? (z & 15) : z) * zB;

  const int tid = threadIdx.x;
  const int w = tid >> 6, l = tid & 63;
  const int wr = w >> 1, wc = w & 1;
  const int ll = l & 15, lg = l >> 4;
  const int bm = blockIdx.x * 128, bn = blockIdx.y * 128;
  const int arow = tid >> 2, acol = (tid & 3) * 8;

  const short* Ap0 = Ab + (size_t)(bm + arow) * ldA + acol;
  const short* Ap1 = Ab + (size_t)(bm + arow + 64) * ldA + acol;
  const short* Bp0 = Bb + (size_t)(bn + arow) * ldB + acol;
  const short* Bp1 = Bb + (size_t)(bn + arow + 64) * ldB + acol;

  f32x4 acc[4][4];
#pragma unroll
  for (int i = 0; i < 4; ++i)
#pragma unroll
    for (int j = 0; j < 4; ++j) acc[i][j] = (f32x4){0.f, 0.f, 0.f, 0.f};

  s16x8 a0 = *(const s16x8*)(Ap0);
  s16x8 a1 = *(const s16x8*)(Ap1);
  s16x8 b0 = *(const s16x8*)(Bp0);
  s16x8 b1 = *(const s16x8*)(Bp1);

  for (int k0 = 0; k0 < K; k0 += 32) {
    __syncthreads();
    *(s16x8*)&As[arow * 36 + acol] = a0;
    *(s16x8*)&As[(arow + 64) * 36 + acol] = a1;
    *(s16x8*)&Bs[arow * 36 + acol] = b0;
    *(s16x8*)&Bs[(arow + 64) * 36 + acol] = b1;
    const int kn = k0 + 32;
    if (kn < K) {
      a0 = *(const s16x8*)(Ap0 + kn);
      a1 = *(const s16x8*)(Ap1 + kn);
      b0 = *(const s16x8*)(Bp0 + kn);
      b1 = *(const s16x8*)(Bp1 + kn);
    }
    __syncthreads();
    s16x8 af[4], bf_[4];
#pragma unroll
    for (int i = 0; i < 4; ++i) {
      af[i] = *(const s16x8*)&As[(wr * 64 + i * 16 + ll) * 36 + lg * 8];
      bf_[i] = *(const s16x8*)&Bs[(wc * 64 + i * 16 + ll) * 36 + lg * 8];
    }
    __builtin_amdgcn_s_setprio(1);
#pragma unroll
    for (int mi = 0; mi < 4; ++mi)
#pragma unroll
      for (int ni = 0; ni < 4; ++ni)
        acc[mi][ni] = MFMA16(af[mi], bf_[ni], acc[mi][ni]);
    __builtin_amdgcn_s_setprio(0);
  }

#pragma unroll
  for (int mi = 0; mi < 4; ++mi)
#pragma unroll
    for (int ni = 0; ni < 4; ++ni)
#pragma unroll
      for (int r = 0; r < 4; ++r) {
        const int row = bm + wr * 64 + mi * 16 + lg * 4 + r;
        const int col = bn + wc * 64 + ni * 16 + ll;
        float v = acc[mi][ni][r];
        if (EPI == 0) {
          Cf[(size_t)row * N + col] = v + bias[col];
        } else if (EPI == 1) {
          if (bias) v += bias[col];
          const int b_ = row >> 10, t = row & 1023, hh = col >> 6, dh = col & 63;
          Cb1[(((size_t)b_ * Hc + hh) * Tc + t) * DHc + dh] = f2bf(v);
        } else if (EPI == 2) {
          v += bias[col];
          const int b_ = row >> 10, t = row & 1023, hh = col >> 6, dh = col & 63;
          const size_t o = (((size_t)b_ * Hc + hh) * Tc + t) * DHc + dh;
          Cb1[o] = f2bf((v + bu[col]) * 0.125f);
          Cb2[o] = f2bf((v + bv[col]) * 0.125f);
        } else {  // EPI == 4: shifted position-score scatter
          short* Pz = Cb1 + (long)z * zC;
          const short pv16 = f2bf(v);
          if (col >= 1023 - row)
            Pz[(size_t)row * 1024 + (col + row - 1023)] = pv16;
          if (row >= 1 && col + row + 1 <= 1023)
            Pz[(size_t)(row - 1) * 1024 + (col + row + 1)] = pv16;
          if (col == 1023 && row < 1023)
            Pz[(size_t)row * 1024 + row + 1] = 0;
        }
      }
}

// ---------------------------------------------------------------------------
// Flash attention, q-tile 64, 4 waves (16 q-rows each), k-tile 128.
// Pos term read directly from SHIFTED table: s[q][k] += Pshift[q*1024+k]
// (contiguous 32B segments per 16-lane group; loads issued before QK^T).
// ---------------------------------------------------------------------------
__global__ __launch_bounds__(256) void flash_attn(
    const short* __restrict__ Qu, const short* __restrict__ Kg,
    const short* __restrict__ Vg, const short* __restrict__ PS,
    short* __restrict__ ctx, int b0) {
  __shared__ short Kt[128 * 72];   // [key][dh], pad->72          18.0 KB
  __shared__ short Vt[64 * 136];   // [dh][key^swz], pad->136     17.0 KB
  __shared__ short PQ[64 * 136];   // Q stage (stride 72) then P  17.0 KB

  const int tid = threadIdx.x;
  const int w = tid >> 6, l = tid & 63;
  const int ll = l & 15, lg = l >> 4;
  const int qt = blockIdx.x, h = blockIdx.y, bl = blockIdx.z;
  const int b = b0 + bl;
  const int q0 = qt * 64;
  const int qw = q0 + w * 16;   // wave's q base

  const size_t bh = (size_t)b * Hc + h;
  const short* Qgp = Qu + (bh * Tc + q0) * DHc;
  const short* Kgp = Kg + bh * Tc * DHc;
  const short* Vgp = Vg + bh * Tc * DHc;
  const short* PSg = PS + ((size_t)(bl * Hc + h) << 20);

  // ---- stage Q tile 64x64 (stride 72), pull A-frags to registers ----
#pragma unroll
  for (int i = 0; i < 2; ++i) {
    const int c = tid + i * 256;             // 512 chunks of 8
    const int row = c >> 3, col8 = (c & 7) * 8;
    *(s16x8*)&PQ[row * 72 + col8] = *(const s16x8*)(Qgp + (size_t)row * 64 + col8);
  }
  __syncthreads();
  s16x8 qa[2];
#pragma unroll
  for (int ks = 0; ks < 2; ++ks)
    qa[ks] = *(const s16x8*)&PQ[(w * 16 + ll) * 72 + ks * 32 + lg * 8];

  f32x4 o[4];
#pragma unroll
  for (int cd = 0; cd < 4; ++cd) o[cd] = (f32x4){0.f, 0.f, 0.f, 0.f};
  float m_run[4], l_run[4];
#pragma unroll
  for (int r = 0; r < 4; ++r) { m_run[r] = -3.0e38f; l_run[r] = 0.f; }

  for (int kt = 0; kt < 8; ++kt) {
    // 1. K/V tile loads (consumed right after barrier A)
    s16x8 kr[4], vr[4];
#pragma unroll
    for (int i = 0; i < 4; ++i) {
      const int c = tid + i * 256;           // 1024 chunks of 8 (128x64)
      const int row = c >> 3, col8 = (c & 7) * 8;
      kr[i] = *(const s16x8*)(Kgp + (size_t)(kt * 128 + row) * 64 + col8);
      vr[i] = *(const s16x8*)(Vgp + (size_t)(kt * 128 + row) * 64 + col8);
    }
    // 2. shifted-pos loads, issued early, consumed after QK^T
    short pg[8][4];
    {
      const short* pbase = PSg + (size_t)(qw + lg * 4) * 1024 + kt * 128 + ll;
#pragma unroll
      for (int ci = 0; ci < 8; ++ci)
#pragma unroll
        for (int r = 0; r < 4; ++r)
          pg[ci][r] = pbase[r * 1024 + ci * 16];
    }
    __syncthreads();  // A: prev-iter LDS reads (and initial qa reads) done
#pragma unroll
    for (int i = 0; i < 4; ++i) {
      const int c = tid + i * 256;
      const int row = c >> 3, col8 = (c & 7) * 8;
      *(s16x8*)&Kt[row * 72 + col8] = kr[i];
#pragma unroll
      for (int e = 0; e < 8; ++e) {
        const int d = col8 + e;
        Vt[d * 136 + (row ^ ((d >> 3) << 4))] = vr[i][e];
      }
    }
    __syncthreads();  // B: staging visible

    // ---- QK^T ----
    f32x4 s[8];
#pragma unroll
    for (int ci = 0; ci < 8; ++ci) s[ci] = (f32x4){0.f, 0.f, 0.f, 0.f};
#pragma unroll
    for (int ks = 0; ks < 2; ++ks) {
      s16x8 kb[8];
#pragma unroll
      for (int ci = 0; ci < 8; ++ci)
        kb[ci] = *(const s16x8*)&Kt[(ci * 16 + ll) * 72 + ks * 32 + lg * 8];
      __builtin_amdgcn_s_setprio(1);
#pragma unroll
      for (int ci = 0; ci < 8; ++ci)
        s[ci] = MFMA16(qa[ks], kb[ci], s[ci]);
      __builtin_amdgcn_s_setprio(0);
    }

    // ---- add shifted position ----
#pragma unroll
    for (int ci = 0; ci < 8; ++ci)
#pragma unroll
      for (int r = 0; r < 4; ++r) s[ci][r] += bf2f(pg[ci][r]);

    // ---- online softmax (rows live in 16-lane groups) ----
    float fac[4];
#pragma unroll
    for (int r = 0; r < 4; ++r) {
      float mx = s[0][r];
#pragma unroll
      for (int ci = 1; ci < 8; ++ci) mx = fmaxf(mx, s[ci][r]);
      mx = fmaxf(mx, __shfl_xor(mx, 1));
      mx = fmaxf(mx, __shfl_xor(mx, 2));
      mx = fmaxf(mx, __shfl_xor(mx, 4));
      mx = fmaxf(mx, __shfl_xor(mx, 8));
      const float mnew = fmaxf(m_run[r], mx);
      const float f = __expf(m_run[r] - mnew);
      float lsum = 0.f;
#pragma unroll
      for (int ci = 0; ci < 8; ++ci) {
        const float e = __expf(s[ci][r] - mnew);
        s[ci][r] = e;
        lsum += e;
      }
      lsum += __shfl_xor(lsum, 1);
      lsum += __shfl_xor(lsum, 2);
      lsum += __shfl_xor(lsum, 4);
      lsum += __shfl_xor(lsum, 8);
      m_run[r] = mnew;
      l_run[r] = l_run[r] * f + lsum;
      fac[r] = f;
    }
#pragma unroll
    for (int cd = 0; cd < 4; ++cd)
#pragma unroll
      for (int r = 0; r < 4; ++r) o[cd][r] *= fac[r];

    // ---- P -> LDS (wave-local rows; in-wave DS ordering suffices) ----
#pragma unroll
    for (int ci = 0; ci < 8; ++ci)
#pragma unroll
      for (int r = 0; r < 4; ++r)
        PQ[(w * 16 + lg * 4 + r) * 136 + ci * 16 + ll] = f2bf(s[ci][r]);
    asm volatile("s_waitcnt lgkmcnt(0)" ::: "memory");

    // ---- PV ----
#pragma unroll
    for (int ks = 0; ks < 4; ++ks) {
      s16x8 pa = *(const s16x8*)&PQ[(w * 16 + ll) * 136 + ks * 32 + lg * 8];
      s16x8 vv[4];
#pragma unroll
      for (int cd = 0; cd < 4; ++cd) {
        const int d = cd * 16 + ll;
        vv[cd] = *(const s16x8*)&Vt[d * 136 + ((ks * 32 + lg * 8) ^ ((d >> 3) << 4))];
      }
      __builtin_amdgcn_s_setprio(1);
#pragma unroll
      for (int cd = 0; cd < 4; ++cd) o[cd] = MFMA16(pa, vv[cd], o[cd]);
      __builtin_amdgcn_s_setprio(0);
    }
  }

  // ---- finalize: /l, write ctx [b, t, h*64+d] bf16 ----
#pragma unroll
  for (int r = 0; r < 4; ++r) {
    const float inv = 1.f / l_run[r];
    const int row = qw + lg * 4 + r;
#pragma unroll
    for (int cd = 0; cd < 4; ++cd) {
      const int d = cd * 16 + ll;
      ctx[((size_t)b * Tc + row) * DIMc + h * DHc + d] = f2bf(o[cd][r] * inv);
    }
  }
}

// ---------------------------------------------------------------------------
extern "C" void kernel_launch(void* const* d_in, const int* in_sizes, int n_in,
                              void* d_out, int out_size, void* d_ws,
                              size_t ws_size, hipStream_t stream) {
  const float* x   = (const float*)d_in[0];
  const float* pos = (const float*)d_in[1];
  // d_in[2] = mask (all-True, unused)
  const float* Wq  = (const float*)d_in[3];
  const float* bq  = (const float*)d_in[4];
  const float* Wk  = (const float*)d_in[5];
  const float* bk  = (const float*)d_in[6];
  const float* Wv  = (const float*)d_in[7];
  const float* bv  = (const float*)d_in[8];
  const float* Wp  = (const float*)d_in[9];
  const float* Wo  = (const float*)d_in[10];
  const float* bo  = (const float*)d_in[11];
  const float* pbu = (const float*)d_in[12];
  const float* pbv = (const float*)d_in[13];
  float* out = (float*)d_out;

  char* ws = (char*)d_ws;
  const size_t MB = 1024 * 1024;
  short* xb  = (short*)(ws + 0 * MB);    // x bf16        8 MB
  short* pb  = (short*)(ws + 8 * MB);    // pos bf16      2 MB
  short* Wqb = (short*)(ws + 10 * MB);
  short* Wkb = (short*)(ws + 12 * MB);
  short* Wvb = (short*)(ws + 14 * MB);
  short* Wpb = (short*)(ws + 16 * MB);
  short* Wob = (short*)(ws + 18 * MB);
  short* Quw = (short*)(ws + 20 * MB);   // (q+bq+bu)/8  [b,h,t,64] 8 MB
  short* Qvw = (short*)(ws + 28 * MB);   // (q+bq+bv)/8  [b,h,t,64] 8 MB
  short* Kw  = (short*)(ws + 36 * MB);   // [b,h,t,64]    8 MB
  short* Vw  = (short*)(ws + 44 * MB);   // [b,h,t,64]    8 MB
  short* Pw  = (short*)(ws + 52 * MB);   // [h,t,64]      2 MB
  short* PSw = (short*)(ws + 54 * MB);   // Pshift slice [2b*16h][1024][1024] 64 MB
  short* Cw  = (short*)(ws + 118 * MB);  // ctx bf16 [b,t,1024]  8 MB

  const dim3 blk(256);
  auto cast = [&](const float* in, short* o_, int n) {
    hipLaunchKernelGGL(cast_f32_bf16, dim3(n / 2048), blk, 0, stream, in, o_, n);
  };
  cast(x, xb, 4194304);
  cast(pos, pb, 1048576);
  cast(Wq, Wqb, 1048576);
  cast(Wk, Wkb, 1048576);
  cast(Wv, Wvb, 1048576);
  cast(Wp, Wpb, 1048576);
  cast(Wo, Wob, 1048576);

  // projections
  hipLaunchKernelGGL((mfma_gemm<2>), dim3(32, 8, 1), blk, 0, stream,
                     xb, Wqb, bq, nullptr, Quw, Qvw, pbu, pbv,
                     1024, 1024, 1024, 1024, 0L, 0L, 0L, 0);
  hipLaunchKernelGGL((mfma_gemm<1>), dim3(32, 8, 1), blk, 0, stream,
                     xb, Wkb, bk, nullptr, Kw, nullptr, nullptr, nullptr,
                     1024, 1024, 1024, 1024, 0L, 0L, 0L, 0);
  hipLaunchKernelGGL((mfma_gemm<1>), dim3(32, 8, 1), blk, 0, stream,
                     xb, Wvb, bv, nullptr, Vw, nullptr, nullptr, nullptr,
                     1024, 1024, 1024, 1024, 0L, 0L, 0L, 0);
  hipLaunchKernelGGL((mfma_gemm<1>), dim3(8, 8, 1), blk, 0, stream,
                     pb, Wpb, nullptr, nullptr, Pw, nullptr, nullptr, nullptr,
                     1024, 1024, 1024, 1024, 0L, 0L, 0L, 0);

  // pos_s (shifted-layout write) + flash, sliced over 2 batches (64 MB slice)
  for (int b0 = 0; b0 < 4; b0 += 2) {
    hipLaunchKernelGGL((mfma_gemm<4>), dim3(8, 8, 32), blk, 0, stream,
                       Qvw + (size_t)b0 * 16 * 65536, Pw, nullptr, nullptr, PSw,
                       nullptr, nullptr, nullptr,
                       1024, 64, 64, 64, 65536L, 65536L, 1L << 20, 1);
    hipLaunchKernelGGL(flash_attn, dim3(16, 16, 2), blk, 0, stream,
                       Quw, Kw, Vw, PSw, Cw, b0);
  }

  // output projection (f32 out)
  hipLaunchKernelGGL((mfma_gemm<0>), dim3(32, 8, 1), blk, 0, stream,
                     Cw, Wob, bo, out, nullptr, nullptr, nullptr, nullptr,
                     1024, 1024, 1024, 1024, 0L, 0L, 0L, 0);
}